// Round 2
// baseline (11737.347 us; speedup 1.0000x reference)
//
#include <hip/hip_runtime.h>
#include <hip/hip_bf16.h>

// ---------------------------------------------------------------------------
// 2-layer tanh RNN:  I=H=1024, B=64, S=512.
//   xp   = x @ Wx + b            (big parallel GEMM, f16 MFMA)
//   h_t1 = tanh(xp_t + h_t @ Wh) (sequential; batch-split groups of 16 rows,
//                                 32 col-WGs/group, Wh slice resident in LDS,
//                                 per-step inter-WG barrier per group)
// All matmul operands fp16 (threshold 2e-2; fp16 rounding ~5e-4 rel).
// ---------------------------------------------------------------------------

typedef _Float16 f16x8 __attribute__((ext_vector_type(8)));
typedef float    f32x4 __attribute__((ext_vector_type(4)));

#define MFMA16(a, b, c) __builtin_amdgcn_mfma_f32_16x16x32_f16((a), (b), (c), 0, 0, 0)

// ---------------------------------------------------------------------------
// prep: transpose+convert the 4 weight matrices to f16 [n][k] layout.
// mat 0: Wx0 = W0[0:1024,:]   -> wt + 0
// mat 1: Wh0 = W0[1024:,:]    -> wt + 1M
// mat 2: Wx1 = W1[0:1024,:]   -> wt + 2M
// mat 3: Wh1 = W1[1024:,:]    -> wt + 3M
// ---------------------------------------------------------------------------
__global__ __launch_bounds__(256) void prep_weights(
    const float* __restrict__ W0, const float* __restrict__ W1,
    _Float16* __restrict__ wt)
{
    __shared__ float tl[64][65];
    const int tid  = threadIdx.x;
    const int mat  = blockIdx.x >> 8;
    const int tile = blockIdx.x & 255;
    const int tk = (tile >> 4) << 6;   // k-origin
    const int tn = (tile & 15) << 6;   // n-origin
    const float* src = (mat < 2 ? W0 : W1) + (size_t)((mat & 1) << 10) * 1024;
    _Float16* dst = wt + (size_t)mat * 1024 * 1024;
    const int cx = tid & 63, r0 = tid >> 6;
#pragma unroll
    for (int i = 0; i < 16; ++i) {
        int r = (i << 2) + r0;
        tl[r][cx] = src[(size_t)(tk + r) * 1024 + tn + cx];
    }
    __syncthreads();
#pragma unroll
    for (int i = 0; i < 16; ++i) {
        int rn = (i << 2) + r0;
        dst[(size_t)(tn + rn) * 1024 + tk + cx] = (_Float16)tl[cx][rn];
    }
}

// init hidden state f16 double-buffers. hb layout:
//  [0,65536)        layer0 buf0   [65536,131072)  layer0 buf1
//  [131072,196608)  layer1 buf0   [196608,262144) layer1 buf1
__global__ void h_init(const float* __restrict__ hid, _Float16* __restrict__ hb)
{
    int i = blockIdx.x * 256 + threadIdx.x;   // 131072 total
    float v = hid[i];
    int dst = (i < 65536) ? i : (65536 + i);
    hb[dst] = (_Float16)v;
}

// ---------------------------------------------------------------------------
// GEMM: C[m][n] (f16) = A[m][:1024] @ Bt[n][:1024]^T + bias[n]
// M=32768, N=1024, K=1024.  Tile 128x128, BK=64, 4 waves.
// ASTRIDED: A is fp32 input (B,S,I), row m=(s*64+b) -> input[(b*512+s)*1024].
// else:     A is f16 [m][1024] (layer-0 outputs).
// ---------------------------------------------------------------------------
template <bool ASTRIDED>
__global__ __launch_bounds__(256) void gemm_xproj(
    const void* __restrict__ Ap, const _Float16* __restrict__ Bt,
    const float* __restrict__ bias, _Float16* __restrict__ Cout)
{
    __shared__ _Float16 As[128][72];
    __shared__ _Float16 Bs[128][72];
    const int tid = threadIdx.x;
    const int m0 = blockIdx.y << 7;
    const int n0 = blockIdx.x << 7;
    const int l  = tid & 63;
    const int wv = tid >> 6;
    const int wm = wv >> 1, wn = wv & 1;

    f32x4 acc[4][4];
#pragma unroll
    for (int mt = 0; mt < 4; ++mt)
#pragma unroll
        for (int nt = 0; nt < 4; ++nt) acc[mt][nt] = 0.0f;

    for (int k0 = 0; k0 < 1024; k0 += 64) {
#pragma unroll
        for (int c = tid; c < 1024; c += 256) {
            int row = c >> 3, ch = c & 7;
            f16x8 av;
            if (ASTRIDED) {
                int m = m0 + row;
                int s = m >> 6, b = m & 63;
                const float* srcp = (const float*)Ap + ((size_t)b * 512 + s) * 1024 + k0 + (ch << 3);
                float4 f1 = *(const float4*)srcp;
                float4 f2 = *(const float4*)(srcp + 4);
                av[0] = (_Float16)f1.x; av[1] = (_Float16)f1.y;
                av[2] = (_Float16)f1.z; av[3] = (_Float16)f1.w;
                av[4] = (_Float16)f2.x; av[5] = (_Float16)f2.y;
                av[6] = (_Float16)f2.z; av[7] = (_Float16)f2.w;
            } else {
                av = *(const f16x8*)((const _Float16*)Ap + (size_t)(m0 + row) * 1024 + k0 + (ch << 3));
            }
            *(f16x8*)&As[row][ch << 3] = av;
            f16x8 bv = *(const f16x8*)(Bt + (size_t)(n0 + row) * 1024 + k0 + (ch << 3));
            *(f16x8*)&Bs[row][ch << 3] = bv;
        }
        __syncthreads();
#pragma unroll
        for (int kb = 0; kb < 2; ++kb) {
            f16x8 af[4], bf[4];
#pragma unroll
            for (int mt = 0; mt < 4; ++mt)
                af[mt] = *(const f16x8*)&As[(wm << 6) + (mt << 4) + (l & 15)][(kb << 5) + ((l >> 4) << 3)];
#pragma unroll
            for (int nt = 0; nt < 4; ++nt)
                bf[nt] = *(const f16x8*)&Bs[(wn << 6) + (nt << 4) + (l & 15)][(kb << 5) + ((l >> 4) << 3)];
#pragma unroll
            for (int mt = 0; mt < 4; ++mt)
#pragma unroll
                for (int nt = 0; nt < 4; ++nt)
                    acc[mt][nt] = MFMA16(af[mt], bf[nt], acc[mt][nt]);
        }
        __syncthreads();
    }
#pragma unroll
    for (int nt = 0; nt < 4; ++nt) {
        int n = n0 + (wn << 6) + (nt << 4) + (l & 15);
        float bb = bias[n];
#pragma unroll
        for (int mt = 0; mt < 4; ++mt) {
            int mbase = m0 + (wm << 6) + (mt << 4) + ((l >> 4) << 2);
#pragma unroll
            for (int d = 0; d < 4; ++d)
                Cout[(size_t)(mbase + d) * 1024 + n] = (_Float16)(acc[mt][nt][d] + bb);
        }
    }
}

// ---------------------------------------------------------------------------
// Recurrence. Grid = 128 WGs x 128 threads.
//   g  = blockIdx>>5 : batch group (16 rows: b = g*16..g*16+15)
//   cg = blockIdx&31 : column group (32 cols: n = cg*32..cg*32+31)
// Wh slice [n0..n0+31][0..1023] f16 = 64KB resident in LDS (XOR-swizzled).
// h exchanged via global double buffer; per-group monotonic-counter barrier.
// LAYER==0: writes f16 outputs to out16 (feeds layer-1 GEMM).
// LAYER==1: writes fp32 outputs to d_out (b,s,h layout).
// ---------------------------------------------------------------------------
template <int LAYER>
__global__ __launch_bounds__(128) void rnn_layer(
    const _Float16* __restrict__ Wht,   // [1024][1024] f16 (n-major)
    const _Float16* __restrict__ xp,    // [512][64][1024] f16 (bias folded)
    _Float16* __restrict__ hbuf,        // [2][64][1024] f16 double buffer
    _Float16* __restrict__ out16,       // layer0 out
    float* __restrict__ outF,           // layer1 out (d_out)
    float* __restrict__ hfin,           // final hidden (fp32, d_out tail)
    unsigned* __restrict__ ctr)         // [4] per-group counters (zeroed)
{
    __shared__ _Float16 wlds[32 * 1024];   // 64 KB
    const int tid = threadIdx.x;
    const int g   = blockIdx.x >> 5;
    const int cg  = blockIdx.x & 31;
    const int n0  = cg << 5;
    const int l   = tid & 63;
    const int w   = tid >> 6;

    // --- preload Wh slice into LDS (swizzled: byte ^= (c&7)<<4 within row) ---
    for (int i = 0; i < 32; ++i) {
        int c = i, j = tid;   // c: local col 0..31, j: 16B chunk 0..127
        f16x8 v = *(const f16x8*)(Wht + (size_t)(n0 + c) * 1024 + j * 8);
        *(f16x8*)((char*)wlds + c * 2048 + ((j * 16) ^ ((c & 7) << 4))) = v;
    }
    __syncthreads();

    const int c_local = (w << 4) + (l & 15);      // 0..31
    const char* wrow  = (const char*)wlds + c_local * 2048;
    const int swz     = (c_local & 7) << 4;
    const int jo      = l >> 4;                   // k-chunk lane group 0..3
    const int col     = n0 + c_local;             // global column
    const int rowA    = (g << 4) + (l & 15);      // A-fragment batch row
    const int rbase   = (g << 4) + ((l >> 4) << 2); // D rows: rbase..rbase+3

    unsigned deadf = 0;

    for (int t = 0; t < 512; ++t) {
        const _Float16* hsrc = hbuf + (size_t)(t & 1) * 65536;
        _Float16* hnxt = hbuf + (size_t)((t & 1) ^ 1) * 65536;
        const _Float16* arow = hsrc + (size_t)rowA * 1024 + (jo << 3);

        // prefetch xp for this step (consumed after mfma loop)
        float xpv[4];
#pragma unroll
        for (int d = 0; d < 4; ++d)
            xpv[d] = (float)xp[((size_t)t * 64 + rbase + d) * 1024 + col];

        f32x4 ac0, ac1, ac2, ac3;
        ac0 = 0.0f; ac1 = 0.0f; ac2 = 0.0f; ac3 = 0.0f;
#pragma unroll
        for (int kb = 0; kb < 32; kb += 4) {
            f16x8 a0 = *(const f16x8*)(arow + (kb + 0) * 32);
            f16x8 a1 = *(const f16x8*)(arow + (kb + 1) * 32);
            f16x8 a2 = *(const f16x8*)(arow + (kb + 2) * 32);
            f16x8 a3 = *(const f16x8*)(arow + (kb + 3) * 32);
            f16x8 b0v = *(const f16x8*)(wrow + ((((kb + 0) * 4 + jo) * 16) ^ swz));
            f16x8 b1v = *(const f16x8*)(wrow + ((((kb + 1) * 4 + jo) * 16) ^ swz));
            f16x8 b2v = *(const f16x8*)(wrow + ((((kb + 2) * 4 + jo) * 16) ^ swz));
            f16x8 b3v = *(const f16x8*)(wrow + ((((kb + 3) * 4 + jo) * 16) ^ swz));
            ac0 = MFMA16(a0, b0v, ac0);
            ac1 = MFMA16(a1, b1v, ac1);
            ac2 = MFMA16(a2, b2v, ac2);
            ac3 = MFMA16(a3, b3v, ac3);
        }
        f32x4 acc = (ac0 + ac1) + (ac2 + ac3);

#pragma unroll
        for (int d = 0; d < 4; ++d) {
            int r = rbase + d;
            size_t sb = (size_t)t * 64 + r;
            float hv = tanhf(acc[d] + xpv[d]);
            hnxt[(size_t)r * 1024 + col] = (_Float16)hv;
            if (LAYER == 0) {
                out16[sb * 1024 + col] = (_Float16)hv;
            } else {
                outF[((size_t)r * 512 + t) * 1024 + col] = hv;
            }
            if (t == 511) hfin[(size_t)r * 1024 + col] = hv;
        }

        if (t < 511) {
            __syncthreads();   // both waves done writing
            if (tid == 0) {
                __threadfence();                       // release (wb to coherent pt)
                atomicAdd(&ctr[g], 1u);                // device-scope
                unsigned target = 32u * (unsigned)(t + 1);
                if (!deadf) {
                    unsigned spins = 0;
                    while (__hip_atomic_load(&ctr[g], __ATOMIC_RELAXED,
                                             __HIP_MEMORY_SCOPE_AGENT) < target) {
                        __builtin_amdgcn_s_sleep(4);
                        if (++spins > (1u << 22)) { deadf = 1; break; }
                    }
                }
                __threadfence();                       // acquire (inv L1/L2)
            }
            __syncthreads();
        }
    }
}

// ---------------------------------------------------------------------------
extern "C" void kernel_launch(void* const* d_in, const int* in_sizes, int n_in,
                              void* d_out, int out_size, void* d_ws, size_t ws_size,
                              hipStream_t stream)
{
    const float* input  = (const float*)d_in[0];   // (64,512,1024)
    const float* hidden = (const float*)d_in[1];   // (2,64,1024)
    const float* W0     = (const float*)d_in[2];   // (2048,1024)
    const float* b0     = (const float*)d_in[3];   // (1,1024)
    const float* W1     = (const float*)d_in[4];   // (2048,1024)
    const float* b1     = (const float*)d_in[5];   // (1,1024)
    float* out = (float*)d_out;

    char* ws = (char*)d_ws;
    unsigned* ctr  = (unsigned*)ws;                                   // 256 B
    _Float16* wt   = (_Float16*)(ws + 4096);                          // 8 MB
    _Float16* hb   = (_Float16*)(ws + 4096 + 8u * 1024 * 1024);       // 512 KB
    _Float16* xp   = (_Float16*)(ws + 16u * 1024 * 1024);             // 64 MB
    _Float16* o16  = (_Float16*)(ws + 16u * 1024 * 1024 + 67108864u); // 64 MB

    float* hfin0 = out + 33554432;            // hidden_final layer 0
    float* hfin1 = out + 33554432 + 65536;    // hidden_final layer 1

    hipMemsetAsync(ctr, 0, 256, stream);
    hipLaunchKernelGGL(prep_weights, dim3(1024), dim3(256), 0, stream, W0, W1, wt);
    hipLaunchKernelGGL(h_init, dim3(512), dim3(256), 0, stream, hidden, hb);

    // layer 0: xp0 = input @ Wx0 + b0
    hipLaunchKernelGGL((gemm_xproj<true>), dim3(8, 256), dim3(256), 0, stream,
                       (const void*)input, wt + 0 * 1048576, b0, xp);
    hipLaunchKernelGGL((rnn_layer<0>), dim3(128), dim3(128), 0, stream,
                       wt + 1 * 1048576, xp, hb, o16, (float*)nullptr, hfin0, ctr);

    // layer 1: xp1 = out0 @ Wx1 + b1
    hipLaunchKernelGGL((gemm_xproj<false>), dim3(8, 256), dim3(256), 0, stream,
                       (const void*)o16, wt + 2 * 1048576, b1, xp);
    hipLaunchKernelGGL((rnn_layer<1>), dim3(128), dim3(128), 0, stream,
                       wt + 3 * 1048576, xp, hb + 131072, (_Float16*)nullptr, out, hfin1,
                       ctr + 4);
}

// Round 4
// 9008.347 us; speedup vs baseline: 1.3029x; 1.3029x over previous
//
#include <hip/hip_runtime.h>
#include <hip/hip_bf16.h>

// ---------------------------------------------------------------------------
// 2-layer tanh RNN:  I=H=1024, B=64, S=512.
//   xp   = x @ Wx + b            (big parallel GEMM, f16 MFMA)
//   h_t1 = tanh(xp_t + h_t @ Wh) (sequential; batch-split groups of 16 rows,
//                                 32 col-WGs/group, Wh slice resident in LDS)
// Round-3/4: NO device-scope fences (wbl2/inv cost ~11us/step in round 2).
// All cross-WG h traffic goes through the coherence point via agent-scope
// atomic loads/stores (sc0/sc1). Barrier = vmcnt drain + atomicAdd + spin.
// Spin bail-out lowered to 2^20 (fail-fast instead of container-killing hang).
// ---------------------------------------------------------------------------

typedef _Float16 f16x8 __attribute__((ext_vector_type(8)));
typedef float    f32x4 __attribute__((ext_vector_type(4)));

#define MFMA16(a, b, c) __builtin_amdgcn_mfma_f32_16x16x32_f16((a), (b), (c), 0, 0, 0)

#define LD64(p)    __hip_atomic_load((const unsigned long long*)(p), __ATOMIC_RELAXED, __HIP_MEMORY_SCOPE_AGENT)
#define ST16(p, v) __hip_atomic_store((unsigned short*)(p), (v), __ATOMIC_RELAXED, __HIP_MEMORY_SCOPE_AGENT)

// ---------------------------------------------------------------------------
// prep: transpose+convert the 4 weight matrices to f16 [n][k] layout.
// ---------------------------------------------------------------------------
__global__ __launch_bounds__(256) void prep_weights(
    const float* __restrict__ W0, const float* __restrict__ W1,
    _Float16* __restrict__ wt)
{
    __shared__ float tl[64][65];
    const int tid  = threadIdx.x;
    const int mat  = blockIdx.x >> 8;
    const int tile = blockIdx.x & 255;
    const int tk = (tile >> 4) << 6;
    const int tn = (tile & 15) << 6;
    const float* src = (mat < 2 ? W0 : W1) + (size_t)((mat & 1) << 10) * 1024;
    _Float16* dst = wt + (size_t)mat * 1024 * 1024;
    const int cx = tid & 63, r0 = tid >> 6;
#pragma unroll
    for (int i = 0; i < 16; ++i) {
        int r = (i << 2) + r0;
        tl[r][cx] = src[(size_t)(tk + r) * 1024 + tn + cx];
    }
    __syncthreads();
#pragma unroll
    for (int i = 0; i < 16; ++i) {
        int rn = (i << 2) + r0;
        dst[(size_t)(tn + rn) * 1024 + tk + cx] = (_Float16)tl[cx][rn];
    }
}

// init hidden state f16 double-buffers (row-major h[64][1024] per buf)
__global__ void h_init(const float* __restrict__ hid, _Float16* __restrict__ hb)
{
    int i = blockIdx.x * 256 + threadIdx.x;   // 131072 total
    float v = hid[i];
    int dst = (i < 65536) ? i : (65536 + i);
    hb[dst] = (_Float16)v;
}

// ---------------------------------------------------------------------------
// GEMM: xp[s][n][b] (f16, packed 4-row chunks) = A @ Bt^T + bias
// M=32768 (s*64+b), N=1024, K=1024.  Tile 128x128, BK=64, 4 waves.
// ---------------------------------------------------------------------------
template <bool ASTRIDED>
__global__ __launch_bounds__(256) void gemm_xproj(
    const void* __restrict__ Ap, const _Float16* __restrict__ Bt,
    const float* __restrict__ bias, _Float16* __restrict__ Cout)
{
    __shared__ _Float16 As[128][72];
    __shared__ _Float16 Bs[128][72];
    const int tid = threadIdx.x;
    const int m0 = blockIdx.y << 7;
    const int n0 = blockIdx.x << 7;
    const int l  = tid & 63;
    const int wv = tid >> 6;
    const int wm = wv >> 1, wn = wv & 1;

    f32x4 acc[4][4];
#pragma unroll
    for (int mt = 0; mt < 4; ++mt)
#pragma unroll
        for (int nt = 0; nt < 4; ++nt) acc[mt][nt] = 0.0f;

    for (int k0 = 0; k0 < 1024; k0 += 64) {
#pragma unroll
        for (int c = tid; c < 1024; c += 256) {
            int row = c >> 3, ch = c & 7;
            f16x8 av;
            if (ASTRIDED) {
                int m = m0 + row;
                int s = m >> 6, b = m & 63;
                const float* srcp = (const float*)Ap + ((size_t)b * 512 + s) * 1024 + k0 + (ch << 3);
                float4 f1 = *(const float4*)srcp;
                float4 f2 = *(const float4*)(srcp + 4);
                av[0] = (_Float16)f1.x; av[1] = (_Float16)f1.y;
                av[2] = (_Float16)f1.z; av[3] = (_Float16)f1.w;
                av[4] = (_Float16)f2.x; av[5] = (_Float16)f2.y;
                av[6] = (_Float16)f2.z; av[7] = (_Float16)f2.w;
            } else {
                av = *(const f16x8*)((const _Float16*)Ap + (size_t)(m0 + row) * 1024 + k0 + (ch << 3));
            }
            *(f16x8*)&As[row][ch << 3] = av;
            f16x8 bv = *(const f16x8*)(Bt + (size_t)(n0 + row) * 1024 + k0 + (ch << 3));
            *(f16x8*)&Bs[row][ch << 3] = bv;
        }
        __syncthreads();
#pragma unroll
        for (int kb = 0; kb < 2; ++kb) {
            f16x8 af[4], bf[4];
#pragma unroll
            for (int mt = 0; mt < 4; ++mt)
                af[mt] = *(const f16x8*)&As[(wm << 6) + (mt << 4) + (l & 15)][(kb << 5) + ((l >> 4) << 3)];
#pragma unroll
            for (int nt = 0; nt < 4; ++nt)
                bf[nt] = *(const f16x8*)&Bs[(wn << 6) + (nt << 4) + (l & 15)][(kb << 5) + ((l >> 4) << 3)];
#pragma unroll
            for (int mt = 0; mt < 4; ++mt)
#pragma unroll
                for (int nt = 0; nt < 4; ++nt)
                    acc[mt][nt] = MFMA16(af[mt], bf[nt], acc[mt][nt]);
        }
        __syncthreads();
    }
    // epilogue: xp[s][n][b] packed 8B (4 consecutive b per thread)
#pragma unroll
    for (int nt = 0; nt < 4; ++nt) {
        int n = n0 + (wn << 6) + (nt << 4) + (l & 15);
        float bb = bias[n];
#pragma unroll
        for (int mt = 0; mt < 4; ++mt) {
            int mbase = m0 + (wm << 6) + (mt << 4) + ((l >> 4) << 2);
            int s = mbase >> 6, b = mbase & 63;
            union { _Float16 h[4]; unsigned long long u; } q;
#pragma unroll
            for (int d = 0; d < 4; ++d) q.h[d] = (_Float16)(acc[mt][nt][d] + bb);
            *(unsigned long long*)(Cout + ((size_t)s * 1024 + n) * 64 + b) = q.u;
        }
    }
}

// ---------------------------------------------------------------------------
// Recurrence. Grid = 128 WGs x 128 threads.
//   g  = blockIdx>>5 : batch group (16 rows)    cg = blockIdx&31 : 32 cols
// Wh slice 64KB in LDS (XOR-swizzled). h exchange: agent-scope (MALL) only.
// ---------------------------------------------------------------------------
template <int LAYER>
__global__ __launch_bounds__(128) void rnn_layer(
    const _Float16* __restrict__ Wht,   // [1024][1024] f16 (n-major)
    const _Float16* __restrict__ xp,    // [512][1024][64] f16 (bias folded)
    _Float16* __restrict__ hbuf,        // [2][64][1024] f16 double buffer
    _Float16* __restrict__ out16,       // layer0 out [t*64+b][1024]
    float* __restrict__ outF,           // layer1 out (b,s,h)
    float* __restrict__ hfin,           // final hidden
    unsigned* __restrict__ ctr)         // per-group counters (zeroed)
{
    __shared__ _Float16 wlds[32 * 1024];   // 64 KB
    const int tid = threadIdx.x;
    const int g   = blockIdx.x >> 5;
    const int cg  = blockIdx.x & 31;
    const int n0  = cg << 5;
    const int l   = tid & 63;
    const int w   = tid >> 6;

    for (int i = 0; i < 32; ++i) {
        int c = i, j = tid;
        f16x8 v = *(const f16x8*)(Wht + (size_t)(n0 + c) * 1024 + j * 8);
        *(f16x8*)((char*)wlds + c * 2048 + ((j * 16) ^ ((c & 7) << 4))) = v;
    }
    __syncthreads();

    const int c_local = (w << 4) + (l & 15);
    const char* wrow  = (const char*)wlds + c_local * 2048;
    const int swz     = (c_local & 7) << 4;
    const int jo      = l >> 4;
    const int col     = n0 + c_local;
    const int rowA    = (g << 4) + (l & 15);
    const int rbase   = (g << 4) + ((l >> 4) << 2);

    unsigned deadf = 0;

    // prefetch xp for t=0 (normal cached load; xp written by prior dispatch)
    unsigned long long xpu =
        *(const unsigned long long*)(xp + ((size_t)0 * 1024 + col) * 64 + rbase);

    for (int t = 0; t < 512; ++t) {
        const _Float16* hsrc = hbuf + (size_t)(t & 1) * 65536;
        _Float16* hnxt = hbuf + (size_t)((t & 1) ^ 1) * 65536;
        // A-row base as 8B units, offset by this lane's k-chunk (jo)
        const unsigned long long* ap =
            (const unsigned long long*)(hsrc + (size_t)rowA * 1024) + (jo << 1);

        f32x4 ac0, ac1, ac2, ac3;
        ac0 = 0.0f; ac1 = 0.0f; ac2 = 0.0f; ac3 = 0.0f;
#pragma unroll
        for (int kb = 0; kb < 32; kb += 4) {
            union { f16x8 v; unsigned long long u[2]; } a0, a1, a2, a3;
            a0.u[0] = LD64(ap + (kb + 0) * 8); a0.u[1] = LD64(ap + (kb + 0) * 8 + 1);
            a1.u[0] = LD64(ap + (kb + 1) * 8); a1.u[1] = LD64(ap + (kb + 1) * 8 + 1);
            a2.u[0] = LD64(ap + (kb + 2) * 8); a2.u[1] = LD64(ap + (kb + 2) * 8 + 1);
            a3.u[0] = LD64(ap + (kb + 3) * 8); a3.u[1] = LD64(ap + (kb + 3) * 8 + 1);
            f16x8 b0v = *(const f16x8*)(wrow + ((((kb + 0) * 4 + jo) * 16) ^ swz));
            f16x8 b1v = *(const f16x8*)(wrow + ((((kb + 1) * 4 + jo) * 16) ^ swz));
            f16x8 b2v = *(const f16x8*)(wrow + ((((kb + 2) * 4 + jo) * 16) ^ swz));
            f16x8 b3v = *(const f16x8*)(wrow + ((((kb + 3) * 4 + jo) * 16) ^ swz));
            ac0 = MFMA16(a0.v, b0v, ac0);
            ac1 = MFMA16(a1.v, b1v, ac1);
            ac2 = MFMA16(a2.v, b2v, ac2);
            ac3 = MFMA16(a3.v, b3v, ac3);
        }
        f32x4 acc = (ac0 + ac1) + (ac2 + ac3);

        union { _Float16 h[4]; unsigned long long u; } xq;
        xq.u = xpu;
#pragma unroll
        for (int d = 0; d < 4; ++d) {
            int r = rbase + d;
            float hv = tanhf(acc[d] + (float)xq.h[d]);
            union { _Float16 f; unsigned short s; } cv;
            cv.f = (_Float16)hv;
            ST16(&hnxt[(size_t)r * 1024 + col], cv.s);   // agent-scope (MALL)
            if (LAYER == 0) {
                out16[((size_t)t * 64 + r) * 1024 + col] = cv.f;  // normal store
            } else {
                outF[((size_t)r * 512 + t) * 1024 + col] = hv;
            }
            if (t == 511) hfin[(size_t)r * 1024 + col] = hv;
        }

        if (t < 511) {
            // prefetch next xp before the barrier (cold HBM latency hidden)
            xpu = *(const unsigned long long*)(xp + ((size_t)(t + 1) * 1024 + col) * 64 + rbase);
            __syncthreads();   // drains vmcnt(0): all waves' h stores at MALL
            if (tid == 0) {
                asm volatile("s_waitcnt vmcnt(0)" ::: "memory");
                atomicAdd(&ctr[g], 1u);                // RMW at coherence point
                unsigned target = 32u * (unsigned)(t + 1);
                if (!deadf) {
                    unsigned spins = 0;
                    while (__hip_atomic_load(&ctr[g], __ATOMIC_RELAXED,
                                             __HIP_MEMORY_SCOPE_AGENT) < target) {
                        __builtin_amdgcn_s_sleep(1);
                        if (++spins > (1u << 20)) { deadf = 1; break; }
                    }
                }
            }
            __syncthreads();
        }
    }
}

// ---------------------------------------------------------------------------
extern "C" void kernel_launch(void* const* d_in, const int* in_sizes, int n_in,
                              void* d_out, int out_size, void* d_ws, size_t ws_size,
                              hipStream_t stream)
{
    const float* input  = (const float*)d_in[0];   // (64,512,1024)
    const float* hidden = (const float*)d_in[1];   // (2,64,1024)
    const float* W0     = (const float*)d_in[2];   // (2048,1024)
    const float* b0     = (const float*)d_in[3];   // (1,1024)
    const float* W1     = (const float*)d_in[4];   // (2048,1024)
    const float* b1     = (const float*)d_in[5];   // (1,1024)
    float* out = (float*)d_out;

    char* ws = (char*)d_ws;
    unsigned* ctr  = (unsigned*)ws;                                   // 256 B
    _Float16* wt   = (_Float16*)(ws + 4096);                          // 8 MB
    _Float16* hb   = (_Float16*)(ws + 4096 + 8u * 1024 * 1024);       // 512 KB
    _Float16* xp   = (_Float16*)(ws + 16u * 1024 * 1024);             // 64 MB
    _Float16* o16  = (_Float16*)(ws + 16u * 1024 * 1024 + 67108864u); // 64 MB

    float* hfin0 = out + 33554432;            // hidden_final layer 0
    float* hfin1 = out + 33554432 + 65536;    // hidden_final layer 1

    hipMemsetAsync(ctr, 0, 256, stream);
    hipLaunchKernelGGL(prep_weights, dim3(1024), dim3(256), 0, stream, W0, W1, wt);
    hipLaunchKernelGGL(h_init, dim3(512), dim3(256), 0, stream, hidden, hb);

    // layer 0: xp0 = input @ Wx0 + b0
    hipLaunchKernelGGL((gemm_xproj<true>), dim3(8, 256), dim3(256), 0, stream,
                       (const void*)input, wt + 0 * 1048576, b0, xp);
    hipLaunchKernelGGL((rnn_layer<0>), dim3(128), dim3(128), 0, stream,
                       wt + 1 * 1048576, xp, hb, o16, (float*)nullptr, hfin0, ctr);

    // layer 1: xp1 = out0 @ Wx1 + b1
    hipLaunchKernelGGL((gemm_xproj<false>), dim3(8, 256), dim3(256), 0, stream,
                       (const void*)o16, wt + 2 * 1048576, b1, xp);
    hipLaunchKernelGGL((rnn_layer<1>), dim3(128), dim3(128), 0, stream,
                       wt + 3 * 1048576, xp, hb + 131072, (_Float16*)nullptr, out, hfin1,
                       ctr + 4);
}

// Round 6
// 3848.841 us; speedup vs baseline: 3.0496x; 2.3405x over previous
//
#include <hip/hip_runtime.h>
#include <hip/hip_bf16.h>

// ---------------------------------------------------------------------------
// 2-layer tanh RNN:  I=H=1024, B=64, S=512.
// Round 5: (a) h exchanged in MFMA-fragment-packed layout so agent loads are
// dense 512B/inst (round 4 scattered 64 lines/inst); (b) barrier rebuilt with
// per-WG arrival slots + wave-parallel poll (round 4: 128 same-line atomicAdd
// per step serialized at one MALL slice).
// ---------------------------------------------------------------------------

typedef _Float16 f16x8 __attribute__((ext_vector_type(8)));
typedef float    f32x4 __attribute__((ext_vector_type(4)));

#define MFMA16(a, b, c) __builtin_amdgcn_mfma_f32_16x16x32_f16((a), (b), (c), 0, 0, 0)

#define LD64(p)     __hip_atomic_load((const unsigned long long*)(p), __ATOMIC_RELAXED, __HIP_MEMORY_SCOPE_AGENT)
#define ST16(p, v)  __hip_atomic_store((unsigned short*)(p), (v), __ATOMIC_RELAXED, __HIP_MEMORY_SCOPE_AGENT)
#define LD32A(p)    __hip_atomic_load((const unsigned*)(p), __ATOMIC_RELAXED, __HIP_MEMORY_SCOPE_AGENT)
#define ST32A(p, v) __hip_atomic_store((unsigned*)(p), (v), __ATOMIC_RELAXED, __HIP_MEMORY_SCOPE_AGENT)

// fragment-packed h layout, per 128KB buffer:
//   byte(b,k) = (b>>4)*32768 + (k>>5)*1024 + ((k>>2)&1)*512
//             + ((b&15) + 16*((k>>3)&3))*8 + (k&3)*2
// wave reads chunk c: lane l gets bytes [c*1024 + l*8) and [c*1024+512 + l*8)
// = two dense 512B regions per instruction pair.

// ---------------------------------------------------------------------------
__global__ __launch_bounds__(256) void prep_weights(
    const float* __restrict__ W0, const float* __restrict__ W1,
    _Float16* __restrict__ wt)
{
    __shared__ float tl[64][65];
    const int tid  = threadIdx.x;
    const int mat  = blockIdx.x >> 8;
    const int tile = blockIdx.x & 255;
    const int tk = (tile >> 4) << 6;
    const int tn = (tile & 15) << 6;
    const float* src = (mat < 2 ? W0 : W1) + (size_t)((mat & 1) << 10) * 1024;
    _Float16* dst = wt + (size_t)mat * 1024 * 1024;
    const int cx = tid & 63, r0 = tid >> 6;
#pragma unroll
    for (int i = 0; i < 16; ++i) {
        int r = (i << 2) + r0;
        tl[r][cx] = src[(size_t)(tk + r) * 1024 + tn + cx];
    }
    __syncthreads();
#pragma unroll
    for (int i = 0; i < 16; ++i) {
        int rn = (i << 2) + r0;
        dst[(size_t)(tn + rn) * 1024 + tk + cx] = (_Float16)tl[cx][rn];
    }
}

// init hidden state into fragment-packed buf0 of each layer
__global__ void h_init(const float* __restrict__ hid, char* __restrict__ hp)
{
    int i = blockIdx.x * 256 + threadIdx.x;   // 131072 total
    float v = hid[i];
    int L = i >> 16, rem = i & 65535;
    int b = rem >> 10, k = rem & 1023;
    size_t byte = (size_t)(b >> 4) * 32768 + (size_t)(k >> 5) * 1024 +
                  (size_t)((k >> 2) & 1) * 512 +
                  (size_t)((b & 15) + 16 * ((k >> 3) & 3)) * 8 + (k & 3) * 2;
    *(_Float16*)(hp + (size_t)L * 262144 + byte) = (_Float16)v;
}

// ---------------------------------------------------------------------------
// GEMM: xp[s][n][b] (f16, packed 4-row chunks) = A @ Bt^T + bias
// ---------------------------------------------------------------------------
template <bool ASTRIDED>
__global__ __launch_bounds__(256) void gemm_xproj(
    const void* __restrict__ Ap, const _Float16* __restrict__ Bt,
    const float* __restrict__ bias, _Float16* __restrict__ Cout)
{
    __shared__ _Float16 As[128][72];
    __shared__ _Float16 Bs[128][72];
    const int tid = threadIdx.x;
    const int m0 = blockIdx.y << 7;
    const int n0 = blockIdx.x << 7;
    const int l  = tid & 63;
    const int wv = tid >> 6;
    const int wm = wv >> 1, wn = wv & 1;

    f32x4 acc[4][4];
#pragma unroll
    for (int mt = 0; mt < 4; ++mt)
#pragma unroll
        for (int nt = 0; nt < 4; ++nt) acc[mt][nt] = 0.0f;

    for (int k0 = 0; k0 < 1024; k0 += 64) {
#pragma unroll
        for (int c = tid; c < 1024; c += 256) {
            int row = c >> 3, ch = c & 7;
            f16x8 av;
            if (ASTRIDED) {
                int m = m0 + row;
                int s = m >> 6, b = m & 63;
                const float* srcp = (const float*)Ap + ((size_t)b * 512 + s) * 1024 + k0 + (ch << 3);
                float4 f1 = *(const float4*)srcp;
                float4 f2 = *(const float4*)(srcp + 4);
                av[0] = (_Float16)f1.x; av[1] = (_Float16)f1.y;
                av[2] = (_Float16)f1.z; av[3] = (_Float16)f1.w;
                av[4] = (_Float16)f2.x; av[5] = (_Float16)f2.y;
                av[6] = (_Float16)f2.z; av[7] = (_Float16)f2.w;
            } else {
                av = *(const f16x8*)((const _Float16*)Ap + (size_t)(m0 + row) * 1024 + k0 + (ch << 3));
            }
            *(f16x8*)&As[row][ch << 3] = av;
            f16x8 bv = *(const f16x8*)(Bt + (size_t)(n0 + row) * 1024 + k0 + (ch << 3));
            *(f16x8*)&Bs[row][ch << 3] = bv;
        }
        __syncthreads();
#pragma unroll
        for (int kb = 0; kb < 2; ++kb) {
            f16x8 af[4], bf[4];
#pragma unroll
            for (int mt = 0; mt < 4; ++mt)
                af[mt] = *(const f16x8*)&As[(wm << 6) + (mt << 4) + (l & 15)][(kb << 5) + ((l >> 4) << 3)];
#pragma unroll
            for (int nt = 0; nt < 4; ++nt)
                bf[nt] = *(const f16x8*)&Bs[(wn << 6) + (nt << 4) + (l & 15)][(kb << 5) + ((l >> 4) << 3)];
#pragma unroll
            for (int mt = 0; mt < 4; ++mt)
#pragma unroll
                for (int nt = 0; nt < 4; ++nt)
                    acc[mt][nt] = MFMA16(af[mt], bf[nt], acc[mt][nt]);
        }
        __syncthreads();
    }
#pragma unroll
    for (int nt = 0; nt < 4; ++nt) {
        int n = n0 + (wn << 6) + (nt << 4) + (l & 15);
        float bb = bias[n];
#pragma unroll
        for (int mt = 0; mt < 4; ++mt) {
            int mbase = m0 + (wm << 6) + (mt << 4) + ((l >> 4) << 2);
            int s = mbase >> 6, b = mbase & 63;
            union { _Float16 h[4]; unsigned long long u; } q;
#pragma unroll
            for (int d = 0; d < 4; ++d) q.h[d] = (_Float16)(acc[mt][nt][d] + bb);
            *(unsigned long long*)(Cout + ((size_t)s * 1024 + n) * 64 + b) = q.u;
        }
    }
}

// ---------------------------------------------------------------------------
// Recurrence. Grid = 128 WGs x 128 threads.
//   g = blockIdx>>5 (16 batch rows), cg = blockIdx&31 (32 cols)
// Wh slice 64KB in LDS. h in fragment-packed agent-scope double buffer.
// Barrier: arrival slot store + wave-parallel slot poll (no atomics).
// ---------------------------------------------------------------------------
template <int LAYER>
__global__ __launch_bounds__(128) void rnn_layer(
    const _Float16* __restrict__ Wht,   // [1024][1024] f16 (n-major)
    const _Float16* __restrict__ xp,    // [512][1024][64] f16 (bias folded)
    char* __restrict__ hpL,             // layer's 2x128KB packed h buffers
    _Float16* __restrict__ out16,       // layer0 out [t*64+b][1024]
    float* __restrict__ outF,           // layer1 out (b,s,h)
    float* __restrict__ hfin,           // final hidden
    char* __restrict__ arrL)            // layer's arrival slots (zeroed)
{
    __shared__ _Float16 wlds[32 * 1024];   // 64 KB
    const int tid = threadIdx.x;
    const int g   = blockIdx.x >> 5;
    const int cg  = blockIdx.x & 31;
    const int n0  = cg << 5;
    const int l   = tid & 63;
    const int w   = tid >> 6;

    for (int i = 0; i < 32; ++i) {
        int c = i, j = tid;
        f16x8 v = *(const f16x8*)(Wht + (size_t)(n0 + c) * 1024 + j * 8);
        *(f16x8*)((char*)wlds + c * 2048 + ((j * 16) ^ ((c & 7) << 4))) = v;
    }
    __syncthreads();

    const int c_local = (w << 4) + (l & 15);
    const char* wrow  = (const char*)wlds + c_local * 2048;
    const int swz     = (c_local & 7) << 4;
    const int col     = n0 + c_local;
    const int rbase   = (g << 4) + ((l >> 4) << 2);
    char* const arrG  = arrL + g * 8192;

    // writer byte base inside a packed buffer (rows rbase..rbase+3, this col)
    const size_t wbyte = (size_t)g * 32768 + (size_t)(col >> 5) * 1024 +
                         (size_t)((col >> 2) & 1) * 512 +
                         (size_t)((col >> 3) & 3) * 128 + (size_t)(col & 3) * 2 +
                         (size_t)((l >> 4) << 2) * 8;
    const size_t lrd = (size_t)l * 8;   // reader lane offset

    unsigned deadf = 0;

    unsigned long long xpu =
        *(const unsigned long long*)(xp + ((size_t)0 * 1024 + col) * 64 + rbase);

    for (int t = 0; t < 512; ++t) {
        const char* hsrcB = hpL + (size_t)(t & 1) * 131072 + (size_t)g * 32768;
        char* hnxtB = hpL + (size_t)((t & 1) ^ 1) * 131072;

        f32x4 ac0, ac1, ac2, ac3;
        ac0 = 0.0f; ac1 = 0.0f; ac2 = 0.0f; ac3 = 0.0f;
#pragma unroll
        for (int kb = 0; kb < 32; kb += 4) {
            union { f16x8 v; unsigned long long u[2]; } a0, a1, a2, a3;
            const char* p0 = hsrcB + (kb + 0) * 1024 + lrd;
            const char* p1 = hsrcB + (kb + 1) * 1024 + lrd;
            const char* p2 = hsrcB + (kb + 2) * 1024 + lrd;
            const char* p3 = hsrcB + (kb + 3) * 1024 + lrd;
            a0.u[0] = LD64(p0); a0.u[1] = LD64(p0 + 512);
            a1.u[0] = LD64(p1); a1.u[1] = LD64(p1 + 512);
            a2.u[0] = LD64(p2); a2.u[1] = LD64(p2 + 512);
            a3.u[0] = LD64(p3); a3.u[1] = LD64(p3 + 512);
            f16x8 b0v = *(const f16x8*)(wrow + ((((kb + 0) * 4 + (l >> 4)) * 16) ^ swz));
            f16x8 b1v = *(const f16x8*)(wrow + ((((kb + 1) * 4 + (l >> 4)) * 16) ^ swz));
            f16x8 b2v = *(const f16x8*)(wrow + ((((kb + 2) * 4 + (l >> 4)) * 16) ^ swz));
            f16x8 b3v = *(const f16x8*)(wrow + ((((kb + 3) * 4 + (l >> 4)) * 16) ^ swz));
            ac0 = MFMA16(a0.v, b0v, ac0);
            ac1 = MFMA16(a1.v, b1v, ac1);
            ac2 = MFMA16(a2.v, b2v, ac2);
            ac3 = MFMA16(a3.v, b3v, ac3);
        }
        f32x4 acc = (ac0 + ac1) + (ac2 + ac3);

        union { _Float16 h[4]; unsigned long long u; } xq;
        xq.u = xpu;
#pragma unroll
        for (int d = 0; d < 4; ++d) {
            int r = rbase + d;
            float hv = tanhf(acc[d] + (float)xq.h[d]);
            union { _Float16 f; unsigned short s; } cv;
            cv.f = (_Float16)hv;
            ST16(hnxtB + wbyte + d * 8, cv.s);   // packed agent store
            if (LAYER == 0) {
                out16[((size_t)t * 64 + r) * 1024 + col] = cv.f;
            } else {
                outF[((size_t)r * 512 + t) * 1024 + col] = hv;
            }
            if (t == 511) hfin[(size_t)r * 1024 + col] = hv;
        }

        if (t < 511) {
            xpu = *(const unsigned long long*)(xp + ((size_t)(t + 1) * 1024 + col) * 64 + rbase);
            __syncthreads();   // drains vmcnt(0): h stores acked at MALL
            if (tid == 0) ST32A(arrG + cg * 4, (unsigned)(t + 1));  // arrival
            unsigned tgt = (unsigned)(t + 1);
            if (!deadf) {
                unsigned rounds = 0;
                for (;;) {
                    unsigned v = LD32A(arrG + (l & 31) * 4);
                    if (__all((int)(v >= tgt))) break;
                    __builtin_amdgcn_s_sleep(1);
                    if (++rounds > (1u << 14)) { deadf = 1; break; }
                }
            }
            __syncthreads();
        }
    }
}

// ---------------------------------------------------------------------------
extern "C" void kernel_launch(void* const* d_in, const int* in_sizes, int n_in,
                              void* d_out, int out_size, void* d_ws, size_t ws_size,
                              hipStream_t stream)
{
    const float* input  = (const float*)d_in[0];   // (64,512,1024)
    const float* hidden = (const float*)d_in[1];   // (2,64,1024)
    const float* W0     = (const float*)d_in[2];   // (2048,1024)
    const float* b0     = (const float*)d_in[3];   // (1,1024)
    const float* W1     = (const float*)d_in[4];   // (2048,1024)
    const float* b1     = (const float*)d_in[5];   // (1,1024)
    float* out = (float*)d_out;

    char* ws = (char*)d_ws;
    char*     arr = ws;                                    // 64KB arrival slots
    char*     hp  = ws + 131072;                           // 2 layers x 256KB
    _Float16* wt  = (_Float16*)(ws + 1048576);             // 8 MB
    _Float16* xp  = (_Float16*)(ws + 16u * 1024 * 1024);   // 64 MB
    _Float16* o16 = (_Float16*)(ws + 16u * 1024 * 1024 + 67108864u); // 64 MB

    float* hfin0 = out + 33554432;
    float* hfin1 = out + 33554432 + 65536;

    hipMemsetAsync(arr, 0, 65536, stream);
    hipLaunchKernelGGL(prep_weights, dim3(1024), dim3(256), 0, stream, W0, W1, wt);
    hipLaunchKernelGGL(h_init, dim3(512), dim3(256), 0, stream, hidden, hp);

    // layer 0
    hipLaunchKernelGGL((gemm_xproj<true>), dim3(8, 256), dim3(256), 0, stream,
                       (const void*)input, wt + 0 * 1048576, b0, xp);
    hipLaunchKernelGGL((rnn_layer<0>), dim3(128), dim3(128), 0, stream,
                       wt + 1 * 1048576, xp, hp, o16, (float*)nullptr, hfin0, arr);

    // layer 1
    hipLaunchKernelGGL((gemm_xproj<false>), dim3(8, 256), dim3(256), 0, stream,
                       (const void*)o16, wt + 2 * 1048576, b1, xp);
    hipLaunchKernelGGL((rnn_layer<1>), dim3(128), dim3(128), 0, stream,
                       wt + 3 * 1048576, xp, hp + 262144, (_Float16*)nullptr, out, hfin1,
                       arr + 32768);
}